// Round 8
// baseline (129.565 us; speedup 1.0000x reference)
//
#include <hip/hip_runtime.h>
#include <hip/hip_bf16.h>
#include <stdint.h>

#define BB 2
#define SS 2048
#define HQ 32
#define HKV 8
#define DD 128
#define WIN 512

typedef __bf16 bf16x8 __attribute__((ext_vector_type(8)));
typedef __bf16 bf16x4 __attribute__((ext_vector_type(4)));
typedef float f32x4 __attribute__((ext_vector_type(4)));

__device__ __forceinline__ bf16x8 cvt8(float4 a, float4 b, float s) {
  bf16x8 r;
  r[0] = (__bf16)(a.x * s); r[1] = (__bf16)(a.y * s);
  r[2] = (__bf16)(a.z * s); r[3] = (__bf16)(a.w * s);
  r[4] = (__bf16)(b.x * s); r[5] = (__bf16)(b.y * s);
  r[6] = (__bf16)(b.z * s); r[7] = (__bf16)(b.w * s);
  return r;
}

struct Stage { float4 ka, ka2; float vr[8]; };

// 1D grid 512 blocks, block 512 = 8 waves.
// Longest-first dispatch + XCD-pinned (b,hkv) columns.
// wave = (wq = wave&3 : 16-row quarter, wh = wave>>2 : head pair)
__global__ __launch_bounds__(512, 2) void attn_kernel(
    const float* __restrict__ qg, const float* __restrict__ kg,
    const float* __restrict__ vg, const float* __restrict__ sinkg,
    float* __restrict__ outg)
{
  const int col = (blockIdx.x & 7) + 8 * ((blockIdx.x >> 3) & 1);
  const int rank = blockIdx.x >> 4;
  const int qtile = rank < 24 ? rank + 8 : 31 - rank;
  const int hkv = col & 7, b = col >> 3;
  const int qb = qtile * 64;
  const int tid = threadIdx.x;
  const int wave = tid >> 6, lane = tid & 63;
  const int wq = wave & 3, wh = wave >> 2;
  const int g = lane >> 4, c = lane & 15;
  const int hq0 = (hkv << 2) + (wh << 1);

  __shared__ __bf16 Kl[2][32 * 128];  // dbuf; 256B rows, XOR-swizzled (row&7)<<4
  __shared__ __bf16 Vt[2][128 * 40];  // dbuf; V transposed [d][kv], 80B rows
  __shared__ __bf16 Pl[16][16 * 40];  // [wave*2+head] P buffers, 80B rows

  const float LOG2E = 1.4426950408889634f;
  const float scale = 0.08838834764831845f * LOG2E;
  const float THR = 12.0f;
  const int qw = qb + wq * 16;
  const int qrow = qw + c;

  bf16x8 qf[2][4];
  #pragma unroll
  for (int hh = 0; hh < 2; ++hh) {
    const float* qp = qg + (((size_t)b * SS + qrow) * HQ + hq0 + hh) * DD;
    #pragma unroll
    for (int ch = 0; ch < 4; ++ch) {
      float4 a = *(const float4*)(qp + ch * 32 + g * 8);
      float4 b2 = *(const float4*)(qp + ch * 32 + g * 8 + 4);
      qf[hh][ch] = cvt8(a, b2, scale);
    }
  }

  const float sk[2] = {sinkg[hq0] * LOG2E, sinkg[hq0 + 1] * LOG2E};

  float mm[2] = {-1e30f, -1e30f}, ll[2] = {0.f, 0.f};
  f32x4 acc[2][8];
  #pragma unroll
  for (int hh = 0; hh < 2; ++hh)
    #pragma unroll
    for (int i = 0; i < 8; ++i) acc[hh][i] = (f32x4){0.f, 0.f, 0.f, 0.f};

  const int t0 = (qb > (WIN - 1) ? (qb - (WIN - 1)) : 0) >> 5;
  const int t1 = (qb + 63) >> 5;

  // staging thread roles; per-tile addr = base + t*KSTEP
  const int krow = tid >> 4, kh = tid & 15;
  const int vd = tid & 127, vc4 = tid >> 7;
  const size_t KSTEP = (size_t)32 * HKV * DD;
  const float* kBase = kg + (((size_t)b * SS + krow) * HKV + hkv) * DD + kh * 8;
  const float* vBase = vg + (((size_t)b * SS + vc4 * 8) * HKV + hkv) * DD + vd;

  Stage sA, sB;
  auto issue = [&](int t, Stage& s) {
    const float* kp = kBase + (size_t)t * KSTEP;
    s.ka = *(const float4*)(kp);
    s.ka2 = *(const float4*)(kp + 4);
    const float* vp = vBase + (size_t)t * KSTEP;
    #pragma unroll
    for (int j = 0; j < 8; ++j) s.vr[j] = vp[(size_t)j * (HKV * DD)];
  };
  auto commit = [&](const Stage& s, int buf) {
    *(bf16x8*)((char*)(&Kl[buf][0]) + krow * 256 + ((kh * 16) ^ ((krow & 7) << 4))) =
        cvt8(s.ka, s.ka2, 1.f);
    bf16x8 w;
    #pragma unroll
    for (int j = 0; j < 8; ++j) w[j] = (__bf16)s.vr[j];
    *(bf16x8*)(&Vt[buf][vd * 40 + vc4 * 8]) = w;
  };

  // prologue: tile t0 -> buf0 (full wait, once); tile t0+1 loads left IN FLIGHT
  issue(t0, sA);
  commit(sA, 0);
  if (t0 + 1 <= t1) issue(t0 + 1, sB);
  asm volatile("s_waitcnt lgkmcnt(0)" ::: "memory");
  __builtin_amdgcn_s_barrier();
  __builtin_amdgcn_sched_barrier(0);
  int cur = 0;

  int i = 0;
  for (int t = t0; t <= t1; ++t, ++i) {
    // issue tile t+2 into the set freed by last commit (parity-peeled: static reg names)
    if ((i & 1) == 0) { if (t + 2 <= t1) issue(t + 2, sA); }
    else              { if (t + 2 <= t1) issue(t + 2, sB); }

    const int kb = t << 5;
    const bool active = !(kb > qw + 15 || kb + 31 < qw - (WIN - 1));
    if (active) {
      const __bf16* Ks = &Kl[cur][0];
      const __bf16* Vs = &Vt[cur][0];

      // ---- QK^T (swapped) both heads: S^T[k][q] ----
      f32x4 s0[2] = {{0.f,0.f,0.f,0.f},{0.f,0.f,0.f,0.f}};
      f32x4 s1[2] = {{0.f,0.f,0.f,0.f},{0.f,0.f,0.f,0.f}};
      __builtin_amdgcn_s_setprio(1);
      #pragma unroll
      for (int ch = 0; ch < 4; ++ch) {
        const int off = (ch * 64 + g * 16) ^ ((c & 7) << 4);
        bf16x8 a0 = *(const bf16x8*)((const char*)Ks + c * 256 + off);
        bf16x8 a1 = *(const bf16x8*)((const char*)Ks + (16 + c) * 256 + off);
        s0[0] = __builtin_amdgcn_mfma_f32_16x16x32_bf16(a0, qf[0][ch], s0[0], 0, 0, 0);
        s1[0] = __builtin_amdgcn_mfma_f32_16x16x32_bf16(a1, qf[0][ch], s1[0], 0, 0, 0);
        s0[1] = __builtin_amdgcn_mfma_f32_16x16x32_bf16(a0, qf[1][ch], s0[1], 0, 0, 0);
        s1[1] = __builtin_amdgcn_mfma_f32_16x16x32_bf16(a1, qf[1][ch], s1[1], 0, 0, 0);
      }
      __builtin_amdgcn_s_setprio(0);

      const bool noMask = (kb + 31 <= qw) && (kb >= qw - (WIN - 16));

      #pragma unroll
      for (int hh = 0; hh < 2; ++hh) {
        float p[8];
        #pragma unroll
        for (int r = 0; r < 4; ++r) { p[r] = s0[hh][r]; p[4 + r] = s1[hh][r]; }
        if (!noMask) {
          #pragma unroll
          for (int t2 = 0; t2 < 2; ++t2)
            #pragma unroll
            for (int r = 0; r < 4; ++r) {
              const int kk = kb + t2 * 16 + g * 4 + r;
              const bool ok = (kk <= qrow) && (qrow - kk < WIN);
              p[t2 * 4 + r] = ok ? p[t2 * 4 + r] : -1e30f;
            }
        }
        float tmax = p[0];
        #pragma unroll
        for (int j = 1; j < 8; ++j) tmax = fmaxf(tmax, p[j]);
        tmax = fmaxf(tmax, __shfl_xor(tmax, 16));
        tmax = fmaxf(tmax, __shfl_xor(tmax, 32));

        const bool resc = __any(tmax > mm[hh] + THR);
        const float mnew = resc ? fmaxf(mm[hh], tmax) : mm[hh];
        float tsum = 0.f;
        if (noMask) {
          #pragma unroll
          for (int j = 0; j < 8; ++j) { p[j] = exp2f(p[j] - mnew); tsum += p[j]; }
        } else {
          #pragma unroll
          for (int j = 0; j < 8; ++j) {
            const float e = (p[j] > -9e29f) ? exp2f(p[j] - mnew) : 0.f;
            p[j] = e; tsum += e;
          }
        }
        tsum += __shfl_xor(tsum, 16);
        tsum += __shfl_xor(tsum, 32);

        if (resc) {
          const float scl = exp2f(mm[hh] - mnew);
          ll[hh] = ll[hh] * scl + tsum;
          #pragma unroll
          for (int dt = 0; dt < 8; ++dt) {
            acc[hh][dt][0] *= scl; acc[hh][dt][1] *= scl;
            acc[hh][dt][2] *= scl; acc[hh][dt][3] *= scl;
          }
          mm[hh] = mnew;
        } else {
          ll[hh] += tsum;
        }

        char* pb = (char*)(&Pl[wave * 2 + hh][0]) + c * 80;
        #pragma unroll
        for (int t2 = 0; t2 < 2; ++t2) {
          bf16x4 w;
          w[0] = (__bf16)p[t2 * 4 + 0]; w[1] = (__bf16)p[t2 * 4 + 1];
          w[2] = (__bf16)p[t2 * 4 + 2]; w[3] = (__bf16)p[t2 * 4 + 3];
          *(bf16x4*)(pb + t2 * 32 + g * 8) = w;
        }
      }

      // ---- PV (operand-swapped): D = V^T * P^T = O^T, q lane-local ----
      bf16x8 pa0 = *(bf16x8*)((char*)(&Pl[wave * 2 + 0][0]) + c * 80 + g * 16);
      bf16x8 pa1 = *(bf16x8*)((char*)(&Pl[wave * 2 + 1][0]) + c * 80 + g * 16);
      __builtin_amdgcn_s_setprio(1);
      #pragma unroll
      for (int dt = 0; dt < 8; ++dt) {
        bf16x8 vv = *(const bf16x8*)(Vs + (dt * 16 + c) * 40 + g * 8);
        acc[0][dt] = __builtin_amdgcn_mfma_f32_16x16x32_bf16(vv, pa0, acc[0][dt], 0, 0, 0);
        acc[1][dt] = __builtin_amdgcn_mfma_f32_16x16x32_bf16(vv, pa1, acc[1][dt], 0, 0, 0);
      }
      __builtin_amdgcn_s_setprio(0);
    }

    if (t < t1) {
      // commit tile t+1 (compiler emits COUNTED vmcnt: t+2's loads stay in flight)
      if ((i & 1) == 0) commit(sB, cur ^ 1);
      else              commit(sA, cur ^ 1);
      asm volatile("s_waitcnt lgkmcnt(0)" ::: "memory");
      __builtin_amdgcn_s_barrier();       // raw barrier: NO vmcnt drain
      __builtin_amdgcn_sched_barrier(0);
      cur ^= 1;
    }
  }

  // ---- epilogue: sink + normalize (all lane-local), float4 stores ----
  #pragma unroll
  for (int hh = 0; hh < 2; ++hh) {
    const float Mf = fmaxf(mm[hh], sk[hh]);
    const float ex = exp2f(mm[hh] - Mf);
    const float denom = ll[hh] * ex + exp2f(sk[hh] - Mf);
    const float fac = ex / denom;
    float* orow = outg + (((size_t)b * SS + qw + c) * HQ + hq0 + hh) * DD;
    #pragma unroll
    for (int dt = 0; dt < 8; ++dt) {
      float4 o;
      o.x = acc[hh][dt][0] * fac; o.y = acc[hh][dt][1] * fac;
      o.z = acc[hh][dt][2] * fac; o.w = acc[hh][dt][3] * fac;
      *(float4*)(orow + dt * 16 + 4 * g) = o;
    }
  }
}

// ---- cache path: inverse-map single-pass fill ----
__global__ void build_inv(const int* __restrict__ ids, int* __restrict__ inv,
                          int npages, int nslots) {
  const int i = threadIdx.x;
  if (i < npages) inv[i] = -1;
  __syncthreads();
  if (i < nslots) inv[ids[i]] = i;
}

__global__ void page_fill(const float* __restrict__ kg, const float* __restrict__ vg,
                          const float* __restrict__ cache_in, const int* __restrict__ inv,
                          float* __restrict__ cache) {
  const int page = blockIdx.x, half = blockIdx.y;
  const int slot = inv[page];
  float4* d4 = (float4*)cache;
  const size_t dbase = (((size_t)page * 2 + half) * 8) * 1024;
  if (slot >= 0) {
    const int b = slot >> 6, blk = slot & 63;
    const float4* s4 = (const float4*)(half ? vg : kg);
    for (int f = threadIdx.x; f < 8192; f += blockDim.x) {
      const int d = f & 31, s = (f >> 5) & 31, h = f >> 10;
      d4[dbase + (size_t)h * 1024 + s * 32 + d] =
          s4[(((size_t)b * SS + blk * 32 + s) * 8 + h) * 32 + d];
    }
  } else {
    const float4* s4 = (const float4*)cache_in;
    for (int f = threadIdx.x; f < 8192; f += blockDim.x)
      d4[dbase + f] = s4[dbase + f];
  }
}

// fallback (no workspace): copy + scatter
__global__ void cache_copy(const float* __restrict__ src, float* __restrict__ dst, int n4) {
  const float4* s = (const float4*)src;
  float4* d = (float4*)dst;
  for (int i = blockIdx.x * blockDim.x + threadIdx.x; i < n4; i += gridDim.x * blockDim.x)
    d[i] = s[i];
}
__global__ void cache_scatter(const float* __restrict__ kg, const float* __restrict__ vg,
                              const int* __restrict__ ids, float* __restrict__ cache) {
  const int slot = blockIdx.x;
  const int half = blockIdx.y;
  const int b = slot >> 6, blk = slot & 63;
  const int page = ids[slot];
  const float4* s4 = (const float4*)(half ? vg : kg);
  float4* d4 = (float4*)cache;
  for (int f = threadIdx.x; f < 8192; f += blockDim.x) {
    const int d = f & 31, s = (f >> 5) & 31, h = f >> 10;
    d4[(((size_t)page * 2 + half) * 8 + h) * 1024 + s * 32 + d] =
        s4[(((size_t)b * SS + blk * 32 + s) * 8 + h) * 32 + d];
  }
}

extern "C" void kernel_launch(void* const* d_in, const int* in_sizes, int n_in,
                              void* d_out, int out_size, void* d_ws, size_t ws_size,
                              hipStream_t stream) {
  const float* q = (const float*)d_in[0];
  const float* k = (const float*)d_in[1];
  const float* v = (const float*)d_in[2];
  const float* cache_in = (const float*)d_in[3];
  const int* ids = (const int*)d_in[4];
  const float* sink = (const float*)d_in[5];
  float* out = (float*)d_out;
  float* cache_out = out + (size_t)BB * SS * HQ * DD; // 16,777,216

  const int nslots = in_sizes[4];                       // B * nb = 128
  const int npages = in_sizes[3] / (2 * HKV * 32 * DD); // 128

  if (ws_size >= (size_t)npages * sizeof(int) && npages <= 1024) {
    int* inv = (int*)d_ws;
    build_inv<<<1, 1024, 0, stream>>>(ids, inv, npages, nslots);
    page_fill<<<dim3(npages, 2), 256, 0, stream>>>(k, v, cache_in, inv, cache_out);
  } else {
    cache_copy<<<4096, 256, 0, stream>>>(cache_in, cache_out, (BB * SS * HKV * DD * 2) / 4);
    cache_scatter<<<dim3(BB * 64, 2), 256, 0, stream>>>(k, v, ids, cache_out);
  }
  attn_kernel<<<512, 512, 0, stream>>>(q, k, v, sink, out);
}

// Round 10
// 108.374 us; speedup vs baseline: 1.1955x; 1.1955x over previous
//
#include <hip/hip_runtime.h>
#include <hip/hip_bf16.h>
#include <stdint.h>

#define BB 2
#define SS 2048
#define HQ 32
#define HKV 8
#define DD 128
#define WIN 512

typedef __bf16 bf16x8 __attribute__((ext_vector_type(8)));
typedef float f32x16 __attribute__((ext_vector_type(16)));

__device__ __forceinline__ bf16x8 cvt8(float4 a, float4 b, float s) {
  bf16x8 r;
  r[0] = (__bf16)(a.x * s); r[1] = (__bf16)(a.y * s);
  r[2] = (__bf16)(a.z * s); r[3] = (__bf16)(a.w * s);
  r[4] = (__bf16)(b.x * s); r[5] = (__bf16)(b.y * s);
  r[6] = (__bf16)(b.z * s); r[7] = (__bf16)(b.w * s);
  return r;
}

__device__ __forceinline__ uint32_t pk2(float lo, float hi) {
  uint32_t w;
  asm("v_cvt_pk_bf16_f32 %0, %1, %2" : "=v"(w) : "v"(lo), "v"(hi));
  return w;
}

// grid 512 blocks, block 512 = 8 waves.  wave = (head = wave>>1, wq = wave&1)
// Block: 64 q-rows x 4 heads of one (b,hkv).  Wave: 32 q-rows x 1 head.
// KVBLK = 64, 32x32x16 MFMA, P kept fully in registers (shfl_xor exchange).
__global__ __launch_bounds__(512, 2) void attn_kernel(
    const float* __restrict__ qg, const float* __restrict__ kg,
    const float* __restrict__ vg, const float* __restrict__ sinkg,
    float* __restrict__ outg)
{
  const int col = (blockIdx.x & 7) + 8 * ((blockIdx.x >> 3) & 1);
  const int rank = blockIdx.x >> 4;
  const int qtile = rank < 24 ? rank + 8 : 31 - rank;  // longest-first
  const int hkv = col & 7, b = col >> 3;
  const int qb = qtile * 64;
  const int tid = threadIdx.x;
  const int wave = tid >> 6, lane = tid & 63;
  const int c5 = lane & 31, hi = lane >> 5;
  const int hq = (hkv << 2) + (wave >> 1);
  const int qw = qb + (wave & 1) * 32;
  const int qrow = qw + c5;

  __shared__ __align__(16) __bf16 Kl[2][64 * 128]; // [kv][d], 256B rows, swizzled
  __shared__ __align__(16) __bf16 Vt[2][128 * 64]; // [d][kv], 128B rows, swizzled

  const float LOG2E = 1.4426950408889634f;
  const float scale = 0.08838834764831845f * LOG2E;
  const float THR = 12.0f;

  // Q fragments: B-operand of S^T = K Q^T.  col=q=c5, k(d) = ch*16 + 8*hi + j
  bf16x8 qf[8];
  {
    const float* qp = qg + (((size_t)b * SS + qrow) * HQ + hq) * DD + hi * 8;
    #pragma unroll
    for (int ch = 0; ch < 8; ++ch) {
      float4 a = *(const float4*)(qp + ch * 16);
      float4 a2 = *(const float4*)(qp + ch * 16 + 4);
      qf[ch] = cvt8(a, a2, scale);
    }
  }
  const float sk = sinkg[hq] * LOG2E;

  float mm = -1e30f, ll = 0.f;
  f32x16 acc[4];
  #pragma unroll
  for (int d = 0; d < 4; ++d)
    #pragma unroll
    for (int r = 0; r < 16; ++r) acc[d][r] = 0.f;

  const int t0 = (qb > (WIN - 1) ? (qb - (WIN - 1)) : 0) >> 6;
  const int t1 = (qb + 63) >> 6;

  // staging roles: K: 64 rows x 8 chunks(16 floats); V: 128 d x 4 slots(16 kv)
  const int krow = tid >> 3, kchunk = tid & 7;
  const int vd = tid & 127, vslot = tid >> 7;
  const size_t KSTEP = (size_t)64 * HKV * DD;
  const float* kBase = kg + (((size_t)b * SS + krow) * HKV + hkv) * DD + kchunk * 16;
  const float* vBase = vg + (((size_t)b * SS + vslot * 16) * HKV + hkv) * DD + vd;

  float4 k0, k1, k2, k3; float vr[16];
  auto issue = [&](int t) {
    const float* kp = kBase + (size_t)t * KSTEP;
    k0 = *(const float4*)(kp);     k1 = *(const float4*)(kp + 4);
    k2 = *(const float4*)(kp + 8); k3 = *(const float4*)(kp + 12);
    const float* vp = vBase + (size_t)t * KSTEP;
    #pragma unroll
    for (int j = 0; j < 16; ++j) vr[j] = vp[(size_t)j * (HKV * DD)];
  };
  const int ksw = ((krow ^ (krow >> 3)) & 7) << 4;
  const int vsw = ((vd ^ (vd >> 3)) & 7) << 4;
  auto commit = [&](int buf) {
    char* kd = (char*)(&Kl[buf][0]) + krow * 256;
    *(bf16x8*)(kd + ((kchunk * 32) ^ ksw)) = cvt8(k0, k1, 1.f);
    *(bf16x8*)(kd + ((kchunk * 32 + 16) ^ ksw)) = cvt8(k2, k3, 1.f);
    char* vdst = (char*)(&Vt[buf][0]) + vd * 128;
    bf16x8 w0, w1;
    #pragma unroll
    for (int j = 0; j < 8; ++j) { w0[j] = (__bf16)vr[j]; w1[j] = (__bf16)vr[8 + j]; }
    *(bf16x8*)(vdst + ((vslot * 32) ^ vsw)) = w0;
    *(bf16x8*)(vdst + ((vslot * 32 + 16) ^ vsw)) = w1;
  };

  issue(t0);
  commit(0);
  __syncthreads();
  int cur = 0;

  // per-lane read swizzles
  const int swA = ((c5 ^ (c5 >> 3)) & 7) << 4;  // K row c5
  const int swB = swA ^ 0x40;                   // K row 32+c5

  for (int t = t0; t <= t1; ++t) {
    if (t < t1) issue(t + 1);
    const int kb = t << 6;
    const char* Ksc = (const char*)&Kl[cur][0];
    const char* Vsc = (const char*)&Vt[cur][0];

    // ---- QK^T: S^T[64 kv][32 q], two 32-kv halves ----
    f32x16 s0, s1;
    #pragma unroll
    for (int r = 0; r < 16; ++r) { s0[r] = 0.f; s1[r] = 0.f; }
    __builtin_amdgcn_s_setprio(1);
    #pragma unroll
    for (int ch = 0; ch < 8; ++ch) {
      const int colb = ch * 32 + hi * 16;
      bf16x8 a0 = *(const bf16x8*)(Ksc + c5 * 256 + (colb ^ swA));
      bf16x8 a1 = *(const bf16x8*)(Ksc + (32 + c5) * 256 + (colb ^ swB));
      s0 = __builtin_amdgcn_mfma_f32_32x32x16_bf16(a0, qf[ch], s0, 0, 0, 0);
      s1 = __builtin_amdgcn_mfma_f32_32x32x16_bf16(a1, qf[ch], s1, 0, 0, 0);
    }
    __builtin_amdgcn_s_setprio(0);

    const bool noMask = (kb + 63 <= qw) && (kb >= qw - (WIN - 32));

    if (!noMask) {
      #pragma unroll
      for (int r = 0; r < 16; ++r) {
        const int lr = (r & 3) + 8 * (r >> 2) + 4 * hi;
        const int kv0 = kb + lr, kv1 = kv0 + 32;
        const bool ok0 = (kv0 <= qrow) && (qrow - kv0 < WIN);
        const bool ok1 = (kv1 <= qrow) && (qrow - kv1 < WIN);
        s0[r] = ok0 ? s0[r] : -1e30f;
        s1[r] = ok1 ? s1[r] : -1e30f;
      }
    }
    float tmax = s0[0];
    #pragma unroll
    for (int r = 1; r < 16; ++r) tmax = fmaxf(tmax, s0[r]);
    #pragma unroll
    for (int r = 0; r < 16; ++r) tmax = fmaxf(tmax, s1[r]);
    tmax = fmaxf(tmax, __shfl_xor(tmax, 32));

    const bool resc = __any(tmax > mm + THR);
    const float mnew = resc ? fmaxf(mm, tmax) : mm;
    float tsum = 0.f;
    if (noMask) {
      #pragma unroll
      for (int r = 0; r < 16; ++r) {
        s0[r] = exp2f(s0[r] - mnew); tsum += s0[r];
        s1[r] = exp2f(s1[r] - mnew); tsum += s1[r];
      }
    } else {
      #pragma unroll
      for (int r = 0; r < 16; ++r) {
        s0[r] = (s0[r] > -9e29f) ? exp2f(s0[r] - mnew) : 0.f; tsum += s0[r];
        s1[r] = (s1[r] > -9e29f) ? exp2f(s1[r] - mnew) : 0.f; tsum += s1[r];
      }
    }
    tsum += __shfl_xor(tsum, 32);

    if (resc) {
      const float scl = exp2f(mm - mnew);
      ll = ll * scl + tsum;
      #pragma unroll
      for (int d = 0; d < 4; ++d)
        #pragma unroll
        for (int r = 0; r < 16; ++r) acc[d][r] *= scl;
      mm = mnew;
    } else {
      ll += tsum;
    }

    // ---- P^T B-frags in-register: lane<->lane^32 exchange per 16-kv quarter ----
    bf16x8 pb[4];
    #pragma unroll
    for (int kvq = 0; kvq < 4; ++kvq) {
      const int bq = (kvq & 1) * 8;
      float e0, e1, e2, e3, e4, e5, e6, e7;
      if (kvq & 2) {
        e0 = s1[bq+0]; e1 = s1[bq+1]; e2 = s1[bq+2]; e3 = s1[bq+3];
        e4 = s1[bq+4]; e5 = s1[bq+5]; e6 = s1[bq+6]; e7 = s1[bq+7];
      } else {
        e0 = s0[bq+0]; e1 = s0[bq+1]; e2 = s0[bq+2]; e3 = s0[bq+3];
        e4 = s0[bq+4]; e5 = s0[bq+5]; e6 = s0[bq+6]; e7 = s0[bq+7];
      }
      const uint32_t A0 = pk2(e0, e1), A1 = pk2(e2, e3);
      const uint32_t B0 = pk2(e4, e5), B1 = pk2(e6, e7);
      const uint32_t XA0 = __shfl_xor(A0, 32), XA1 = __shfl_xor(A1, 32);
      const uint32_t XB0 = __shfl_xor(B0, 32), XB1 = __shfl_xor(B1, 32);
      union { uint4 u; bf16x8 v; } cvu;
      cvu.u.x = hi ? XB0 : A0;
      cvu.u.y = hi ? XB1 : A1;
      cvu.u.z = hi ? B0 : XA0;
      cvu.u.w = hi ? B1 : XA1;
      pb[kvq] = cvu.v;
    }

    // ---- PV: O^T[d][q] = V^T P^T ----
    __builtin_amdgcn_s_setprio(1);
    #pragma unroll
    for (int d = 0; d < 4; ++d) {
      const int rowb = (d * 32 + c5) * 128;
      const int swV = swA ^ ((d & 1) << 6);
      #pragma unroll
      for (int kvq = 0; kvq < 4; ++kvq) {
        bf16x8 va = *(const bf16x8*)(Vsc + rowb + ((kvq * 32 + hi * 16) ^ swV));
        acc[d] = __builtin_amdgcn_mfma_f32_32x32x16_bf16(va, pb[kvq], acc[d], 0, 0, 0);
      }
    }
    __builtin_amdgcn_s_setprio(0);

    if (t < t1) {
      commit(cur ^ 1);
      __syncthreads();
      cur ^= 1;
    }
  }

  // ---- epilogue: sink + normalize (lane-local), float4 stores ----
  {
    const float Mf = fmaxf(mm, sk);
    const float ex = exp2f(mm - Mf);
    const float denom = ll * ex + exp2f(sk - Mf);
    const float fac = ex / denom;
    float* orow = outg + (((size_t)b * SS + qrow) * HQ + hq) * DD;
    #pragma unroll
    for (int d = 0; d < 4; ++d) {
      #pragma unroll
      for (int q4 = 0; q4 < 4; ++q4) {
        float4 o;
        o.x = acc[d][q4 * 4 + 0] * fac;
        o.y = acc[d][q4 * 4 + 1] * fac;
        o.z = acc[d][q4 * 4 + 2] * fac;
        o.w = acc[d][q4 * 4 + 3] * fac;
        *(float4*)(orow + d * 32 + q4 * 8 + 4 * hi) = o;
      }
    }
  }
}

// ---- cache path: inverse-map single-pass fill ----
__global__ void build_inv(const int* __restrict__ ids, int* __restrict__ inv,
                          int npages, int nslots) {
  const int i = threadIdx.x;
  if (i < npages) inv[i] = -1;
  __syncthreads();
  if (i < nslots) inv[ids[i]] = i;
}

__global__ void page_fill(const float* __restrict__ kg, const float* __restrict__ vg,
                          const float* __restrict__ cache_in, const int* __restrict__ inv,
                          float* __restrict__ cache) {
  const int page = blockIdx.x, half = blockIdx.y;
  const int slot = inv[page];
  float4* d4 = (float4*)cache;
  const size_t dbase = (((size_t)page * 2 + half) * 8) * 1024;
  if (slot >= 0) {
    const int b = slot >> 6, blk = slot & 63;
    const float4* s4 = (const float4*)(half ? vg : kg);
    for (int f = threadIdx.x; f < 8192; f += blockDim.x) {
      const int d = f & 31, s = (f >> 5) & 31, h = f >> 10;
      d4[dbase + (size_t)h * 1024 + s * 32 + d] =
          s4[(((size_t)b * SS + blk * 32 + s) * 8 + h) * 32 + d];
    }
  } else {
    const float4* s4 = (const float4*)cache_in;
    for (int f = threadIdx.x; f < 8192; f += blockDim.x)
      d4[dbase + f] = s4[dbase + f];
  }
}

// fallback (no workspace): copy + scatter
__global__ void cache_copy(const float* __restrict__ src, float* __restrict__ dst, int n4) {
  const float4* s = (const float4*)src;
  float4* d = (float4*)dst;
  for (int i = blockIdx.x * blockDim.x + threadIdx.x; i < n4; i += gridDim.x * blockDim.x)
    d[i] = s[i];
}
__global__ void cache_scatter(const float* __restrict__ kg, const float* __restrict__ vg,
                              const int* __restrict__ ids, float* __restrict__ cache) {
  const int slot = blockIdx.x;
  const int half = blockIdx.y;
  const int b = slot >> 6, blk = slot & 63;
  const int page = ids[slot];
  const float4* s4 = (const float4*)(half ? vg : kg);
  float4* d4 = (float4*)cache;
  for (int f = threadIdx.x; f < 8192; f += blockDim.x) {
    const int d = f & 31, s = (f >> 5) & 31, h = f >> 10;
    d4[(((size_t)page * 2 + half) * 8 + h) * 1024 + s * 32 + d] =
        s4[(((size_t)b * SS + blk * 32 + s) * 8 + h) * 32 + d];
  }
}

extern "C" void kernel_launch(void* const* d_in, const int* in_sizes, int n_in,
                              void* d_out, int out_size, void* d_ws, size_t ws_size,
                              hipStream_t stream) {
  const float* q = (const float*)d_in[0];
  const float* k = (const float*)d_in[1];
  const float* v = (const float*)d_in[2];
  const float* cache_in = (const float*)d_in[3];
  const int* ids = (const int*)d_in[4];
  const float* sink = (const float*)d_in[5];
  float* out = (float*)d_out;
  float* cache_out = out + (size_t)BB * SS * HQ * DD; // 16,777,216

  const int nslots = in_sizes[4];                       // B * nb = 128
  const int npages = in_sizes[3] / (2 * HKV * 32 * DD); // 128

  if (ws_size >= (size_t)npages * sizeof(int) && npages <= 1024) {
    int* inv = (int*)d_ws;
    build_inv<<<1, 1024, 0, stream>>>(ids, inv, npages, nslots);
    page_fill<<<dim3(npages, 2), 256, 0, stream>>>(k, v, cache_in, inv, cache_out);
  } else {
    cache_copy<<<4096, 256, 0, stream>>>(cache_in, cache_out, (BB * SS * HKV * DD * 2) / 4);
    cache_scatter<<<dim3(BB * 64, 2), 256, 0, stream>>>(k, v, ids, cache_out);
  }
  attn_kernel<<<512, 512, 0, stream>>>(q, k, v, sink, out);
}